// Round 12
// baseline (136.406 us; speedup 1.0000x reference)
//
#include <hip/hip_runtime.h>
#include <hip/hip_bf16.h>

#define HH 8
#define NNq 2048
#define EPSF 1e-5f
#define LOG2E 1.4426950408889634f

typedef __bf16 bf16x8 __attribute__((ext_vector_type(8)));
typedef float f32x4 __attribute__((ext_vector_type(4)));

typedef const __attribute__((address_space(1))) unsigned int* gas_t;
typedef __attribute__((address_space(3))) unsigned int* las_t;

__device__ __forceinline__ void async16(const void* g, void* l) {
  __builtin_amdgcn_global_load_lds((gas_t)g, (las_t)l, 16, 0, 0);
}
__device__ __forceinline__ void async4(const void* g, void* l) {
  __builtin_amdgcn_global_load_lds((gas_t)g, (las_t)l, 4, 0, 0);
}

__device__ __forceinline__ unsigned short f2bf(float f) {
  union { float f; unsigned int u; } a;
  a.f = f;
  unsigned int r = a.u + 0x7fffu + ((a.u >> 16) & 1u);
  return (unsigned short)(r >> 16);
}

// Chunk-XOR swizzle for bank-conflict-free ds_read_b128 fragments.
__device__ __forceinline__ int swzk(int row, int k) {
  return (k & ~63) | ((((k >> 3) ^ row) & 7) << 3) | (k & 7);
}

// ---------------------------------------------------------------------------
// prep: blocks [0,1024) convert z fp32->bf16 (swizzled); [1024,1280) transpose
// weights fp32->bf16 [n][k] (swizzled); block 1280 zeroes k2max.
// ---------------------------------------------------------------------------
__global__ __launch_bounds__(256) void prep_kernel(
    const float* __restrict__ z, const float* __restrict__ W0,
    const float* __restrict__ W1, const float* __restrict__ W2,
    const float* __restrict__ W3, unsigned short* __restrict__ zb,
    unsigned short* __restrict__ Wt, unsigned int* __restrict__ k2max) {
  __shared__ float Tl[64][68];
  const int t = threadIdx.x;
  const int bx = blockIdx.x;
  if (bx < 1024) {
    const int i = (bx * 256 + t) * 8;
    const int row = i >> 9, k = i & 511;
    const float4 a = *(const float4*)&z[i];
    const float4 b = *(const float4*)&z[i + 4];
    union { unsigned short us[8]; uint4 v; } o;
    o.us[0] = f2bf(a.x); o.us[1] = f2bf(a.y); o.us[2] = f2bf(a.z); o.us[3] = f2bf(a.w);
    o.us[4] = f2bf(b.x); o.us[5] = f2bf(b.y); o.us[6] = f2bf(b.z); o.us[7] = f2bf(b.w);
    *(uint4*)&zb[(row << 9) | swzk(row, k)] = o.v;
  } else if (bx < 1280) {
    const int idx0 = bx - 1024;
    const int wsel = idx0 >> 6, rem = idx0 & 63;
    const int k0 = (rem >> 3) * 64, n0 = (rem & 7) * 64;
    const float* W = (wsel == 0) ? W0 : (wsel == 1) ? W1 : (wsel == 2) ? W2 : W3;
    unsigned short* dst = Wt + (size_t)wsel * 262144;
#pragma unroll
    for (int i = 0; i < 4; ++i) {
      const int idx = t + 256 * i;
      const int row = idx >> 4, cq = (idx & 15) * 4;
      *(float4*)&Tl[row][cq] = *(const float4*)&W[(size_t)(k0 + row) * 512 + n0 + cq];
    }
    __syncthreads();
#pragma unroll
    for (int i = 0; i < 4; ++i) {
      const int idx = t + 256 * i;
      const int nr = idx >> 4, kq = (idx & 15) * 4;
      ushort4 o;
      o.x = f2bf(Tl[kq + 0][nr]);
      o.y = f2bf(Tl[kq + 1][nr]);
      o.z = f2bf(Tl[kq + 2][nr]);
      o.w = f2bf(Tl[kq + 3][nr]);
      const int n = n0 + nr;
      *(ushort4*)&dst[(size_t)n * 512 + swzk(n, k0 + kq)] = o;
    }
  } else {
    k2max[t] = 0u;
  }
}

// ---------------------------------------------------------------------------
// Staged QKV projection + stats. 64 rows x 64 cols (one head) per block.
// grid (64, 8, 3) = 1536 blocks; LDS 32KB -> 5 blocks/CU (latency hiding).
// BK=128 (4 K-iters), swizzle-aware conflict-free fragment reads.
// mode 0: Q bf16 [bh][n][64] + c1/dv/q2. mode 1: K swizzled attn tile +
// k2/k2max. mode 2: V swizzled attn tile (rows=dim, cols=key).
// ---------------------------------------------------------------------------
__global__ __launch_bounds__(256) void gemm_qkv(
    const unsigned short* __restrict__ A, const unsigned short* __restrict__ Wt3,
    const float* __restrict__ bq, const float* __restrict__ bk,
    const float* __restrict__ bvv, unsigned short* __restrict__ Qb,
    unsigned short* __restrict__ Ksw, unsigned short* __restrict__ Vsw,
    float* __restrict__ c1a, float* __restrict__ dva, float* __restrict__ k2a,
    float* __restrict__ q2a, unsigned int* __restrict__ k2max) {
  __shared__ __align__(16) unsigned short S[16384];  // As[64][128] | Bs[64][128]
  __shared__ float wmax[4];

  const int which = blockIdx.z;
  const unsigned short* Wt = Wt3 + (size_t)which * 262144;
  const float* bias = (which == 0) ? bq : (which == 1) ? bk : bvv;

  const int t = threadIdx.x;
  const int w = t >> 6, lane = t & 63, ln = lane & 15, quad = lane >> 4;
  const int r0 = blockIdx.x * 64, h = blockIdx.y;
  const int c0 = h * 64;
  const int b = r0 >> 11, n0 = r0 & 2047;
  const int bh = b * HH + h;

  f32x4 acc[4];
#pragma unroll
  for (int nt = 0; nt < 4; ++nt) acc[nt] = (f32x4)(0.0f);

  const int lr = lane >> 4, lc = (lane & 15) * 8;  // 16 lanes per 256B row

  for (int k0 = 0; k0 < 512; k0 += 128) {
#pragma unroll
    for (int i = 0; i < 4; ++i) {
      async16(A + (size_t)(r0 + w * 16 + i * 4 + lr) * 512 + k0 + lc,
              S + (w * 16 + i * 4) * 128);
      async16(Wt + (size_t)(c0 + w * 16 + i * 4 + lr) * 512 + k0 + lc,
              S + 8192 + (w * 16 + i * 4) * 128);
    }
    __syncthreads();
#pragma unroll
    for (int kk = 0; kk < 128; kk += 32) {
      const int cp = (kk >> 3) + quad;
      const int cs = ((cp & 8) | ((cp ^ (ln & 7)) & 7)) * 8;
      const bf16x8 af = *(const bf16x8*)&S[(w * 16 + ln) * 128 + cs];
#pragma unroll
      for (int nt = 0; nt < 4; ++nt) {
        const bf16x8 bf = *(const bf16x8*)&S[8192 + (nt * 16 + ln) * 128 + cs];
        acc[nt] = __builtin_amdgcn_mfma_f32_16x16x32_bf16(af, bf, acc[nt], 0, 0, 0);
      }
    }
    __syncthreads();
  }

  float x[4][4];  // [nt][r]
#pragma unroll
  for (int nt = 0; nt < 4; ++nt) {
    const float bv = bias[c0 + nt * 16 + ln];
#pragma unroll
    for (int r = 0; r < 4; ++r) x[nt][r] = acc[nt][r] + bv;
  }
  const int rowl = w * 16 + quad * 4;  // +r

  if (which == 0) {
#pragma unroll
    for (int r = 0; r < 4; ++r) {
      float s1 = x[0][r] + x[1][r] + x[2][r] + x[3][r];
#pragma unroll
      for (int off = 1; off < 16; off <<= 1) s1 += __shfl_xor(s1, off, 64);
      const float mu = s1 * (1.0f / 64.0f);
      float s2 = 0.0f, sa = 0.0f;
#pragma unroll
      for (int nt = 0; nt < 4; ++nt) {
        const float dx = x[nt][r] - mu;
        s2 += dx * dx;
        sa += fabsf(dx);
      }
#pragma unroll
      for (int off = 1; off < 16; off <<= 1) {
        s2 += __shfl_xor(s2, off, 64);
        sa += __shfl_xor(sa, off, 64);
      }
      if (ln == 0) {
        const float sigma = sqrtf(s2 * (1.0f / 64.0f) + EPSF);
        const float nf = sa / (sigma + EPSF);
        const float dInv = 1.0f / (__expf(-nf) + 1.0f);
        const int row = bh * NNq + n0 + rowl + r;
        c1a[row] = (0.125f + 2.0f * dInv) * LOG2E;
        dva[row] = dInv * LOG2E;
        q2a[row] = s2 + 64.0f * mu * mu;
      }
    }
#pragma unroll
    for (int nt = 0; nt < 4; ++nt)
#pragma unroll
      for (int r = 0; r < 4; ++r)
        S[(rowl + r) * 72 + nt * 16 + ln] = f2bf(x[nt][r]);
    __syncthreads();
#pragma unroll
    for (int i = 0; i < 2; ++i) {
      const int idx = t + 256 * i;
      const int q = idx >> 3, c = idx & 7;
      *(uint4*)&Qb[((size_t)bh * NNq + n0 + q) * 64 + c * 8] =
          *(const uint4*)&S[q * 72 + c * 8];
    }
  } else if (which == 1) {
    float mx = 0.0f;
#pragma unroll
    for (int r = 0; r < 4; ++r) {
      float s2 = 0.0f;
#pragma unroll
      for (int nt = 0; nt < 4; ++nt) s2 += x[nt][r] * x[nt][r];
#pragma unroll
      for (int off = 1; off < 16; off <<= 1) s2 += __shfl_xor(s2, off, 64);
      if (ln == 0) k2a[bh * NNq + n0 + rowl + r] = s2;
      mx = fmaxf(mx, s2);
    }
#pragma unroll
    for (int off = 16; off < 64; off <<= 1) mx = fmaxf(mx, __shfl_xor(mx, off, 64));
    if (lane == 0) wmax[w] = mx;
#pragma unroll
    for (int nt = 0; nt < 4; ++nt) {
      const int c = nt * 2 + (ln >> 3);
#pragma unroll
      for (int r = 0; r < 4; ++r) {
        const int key = rowl + r;
        S[key * 64 + ((c ^ (key & 7)) * 8) + (ln & 7)] = f2bf(x[nt][r]);
      }
    }
    __syncthreads();
    if (t == 0) {
      const float m = fmaxf(fmaxf(wmax[0], wmax[1]), fmaxf(wmax[2], wmax[3]));
      atomicMax(&k2max[bh * 16], __float_as_uint(m));
    }
    unsigned short* dst = Ksw + ((size_t)bh * 32 + (n0 >> 6)) * 4096;
#pragma unroll
    for (int i = 0; i < 2; ++i) {
      const int idx = t + 256 * i;
      *(uint4*)&dst[idx * 8] = *(const uint4*)&S[idx * 8];
    }
  } else {
#pragma unroll
    for (int nt = 0; nt < 4; ++nt) {
      const int d = nt * 16 + ln;
#pragma unroll
      for (int r = 0; r < 4; ++r) {
        const int key = rowl + r;
        S[d * 64 + (((key >> 3) ^ (d & 7)) * 8) + (key & 7)] = f2bf(x[nt][r]);
      }
    }
    __syncthreads();
    unsigned short* dst = Vsw + ((size_t)bh * 32 + (n0 >> 6)) * 4096;
#pragma unroll
    for (int i = 0; i < 2; ++i) {
      const int idx = t + 256 * i;
      *(uint4*)&dst[idx * 8] = *(const uint4*)&S[idx * 8];
    }
  }
}

// ---------------------------------------------------------------------------
// Flash attention, 512 threads = 8 waves: waves 0-3 keys [0,1024),
// waves 4-7 keys [1024,2048). Fixed-bound softmax; k2 preloaded per half;
// L computed on the MFMA pipe (P x ones) -> no in-loop VALU L adds, no
// end shuffle reduce; Lacc lands in C-layout rows = query like O.
// ---------------------------------------------------------------------------
__global__ __launch_bounds__(512) void attn_kernel(
    const unsigned short* __restrict__ Qb, const unsigned short* __restrict__ Ksw,
    const unsigned short* __restrict__ Vsw, const float* __restrict__ c1a,
    const float* __restrict__ dva, const float* __restrict__ k2a,
    const float* __restrict__ q2a, const unsigned int* __restrict__ k2maxu,
    unsigned short* __restrict__ attnb) {
  // [0,32768): per-half K(8K)+V(8K); aliased as fp32 O partials at the end.
  // [32768,51200): per-half Ps [64][72] bf16; aliased as L storage.
  // [51200,59392): per-half k2 (1024 floats each).
  __shared__ __align__(16) char smem[59392];

  const int t = threadIdx.x;
  const int w8 = t >> 6, lane = t & 63, ln = lane & 15, quad = lane >> 4;
  const int half = w8 >> 2, wl = w8 & 3;
  const int qt = blockIdx.x, bh = blockIdx.y;
  const int b = bh >> 3, h = bh & 7;
  const int q0 = qt * 64;
  const int rowbase = bh * NNq;

  unsigned short* Kt = (unsigned short*)(smem + half * 16384);
  unsigned short* Vt = (unsigned short*)(smem + half * 16384 + 8192);
  unsigned short* Ps = (unsigned short*)(smem + 32768 + half * 9216);
  float* k2h = (float*)(smem + 51200 + half * 4096);

  // Preload this half's k2 (1024 floats) once.
  const float* k2g = k2a + rowbase + half * 1024;
#pragma unroll
  for (int i = 0; i < 4; ++i)
    async4(k2g + wl * 256 + i * 64 + lane, k2h + wl * 256 + i * 64);

  // Q fragment: lane ln holds query q0 + wl*16 + ln (B-operand for S^T).
  const int qg = q0 + wl * 16 + ln;
  const unsigned short* qrow = Qb + ((size_t)rowbase + qg) * 64;
  const bf16x8 aq0 = *(const bf16x8*)(qrow + quad * 8);
  const bf16x8 aq1 = *(const bf16x8*)(qrow + 32 + quad * 8);

  const float k2m = __uint_as_float(k2maxu[bh * 16]);
  const float c1q = c1a[rowbase + qg];
  const float dvq = dva[rowbase + qg];
  const float Mqq = c1q * sqrtf(q2a[rowbase + qg] * k2m);

  const __bf16 onev = (__bf16)1.0f;
  const bf16x8 ones = {onev, onev, onev, onev, onev, onev, onev, onev};

  f32x4 Lacc = (f32x4)(0.0f);
  f32x4 O[4];
#pragma unroll
  for (int nt = 0; nt < 4; ++nt) O[nt] = (f32x4)(0.0f);

  const unsigned short* Kg = Ksw + (size_t)bh * 32 * 4096;
  const unsigned short* Vg = Vsw + (size_t)bh * 32 * 4096;
  const int sw = quad ^ (ln & 7);
  const int sw1 = (4 + quad) ^ (ln & 7);

  for (int kt = 0; kt < 16; ++kt) {
    {
      const size_t tb = (size_t)(half * 16 + kt) * 4096 + wl * 1024;
      async16(Kg + tb + lane * 8, Kt + wl * 1024);
      async16(Kg + tb + 512 + lane * 8, Kt + wl * 1024 + 512);
      async16(Vg + tb + lane * 8, Vt + wl * 1024);
      async16(Vg + tb + 512 + lane * 8, Vt + wl * 1024 + 512);
    }
    __syncthreads();

    // ---- S^T = K Q^T ----
    f32x4 s[4];
#pragma unroll
    for (int nt = 0; nt < 4; ++nt) {
      const unsigned short* kb = Kt + (nt * 16 + ln) * 64;
      const bf16x8 b0 = *(const bf16x8*)(kb + sw * 8);
      const bf16x8 b1 = *(const bf16x8*)(kb + sw1 * 8);
      f32x4 a = (f32x4)(0.0f);
      a = __builtin_amdgcn_mfma_f32_16x16x32_bf16(b0, aq0, a, 0, 0, 0);
      a = __builtin_amdgcn_mfma_f32_16x16x32_bf16(b1, aq1, a, 0, 0, 0);
      s[nt] = a;
    }

    // ---- softmax (scalar per lane) + packed P^T write ----
#pragma unroll
    for (int nt = 0; nt < 4; ++nt) {
      const f32x4 k2v = *(const f32x4*)&k2h[kt * 64 + nt * 16 + quad * 4];
      const float p0 = __builtin_amdgcn_exp2f(c1q * s[nt][0] - dvq * k2v[0] - Mqq);
      const float p1 = __builtin_amdgcn_exp2f(c1q * s[nt][1] - dvq * k2v[1] - Mqq);
      const float p2 = __builtin_amdgcn_exp2f(c1q * s[nt][2] - dvq * k2v[2] - Mqq);
      const float p3 = __builtin_amdgcn_exp2f(c1q * s[nt][3] - dvq * k2v[3] - Mqq);
      union { __hip_bfloat162 h; unsigned int u; } c01, c23;
      c01.h = __float22bfloat162_rn(make_float2(p0, p1));
      c23.h = __float22bfloat162_rn(make_float2(p2, p3));
      uint2 pu; pu.x = c01.u; pu.y = c23.u;
      *(uint2*)&Ps[(wl * 16 + ln) * 72 + nt * 16 + quad * 4] = pu;
    }
    const unsigned short* pr = Ps + (wl * 16 + ln) * 72;
    const bf16x8 pa0 = *(const bf16x8*)(pr + quad * 8);
    const bf16x8 pa1 = *(const bf16x8*)(pr + 32 + quad * 8);

    // ---- L += P * 1 (MFMA pipe; rows = query, same layout as O) ----
    Lacc = __builtin_amdgcn_mfma_f32_16x16x32_bf16(pa0, ones, Lacc, 0, 0, 0);
    Lacc = __builtin_amdgcn_mfma_f32_16x16x32_bf16(pa1, ones, Lacc, 0, 0, 0);

    // ---- O += P V ----
#pragma unroll
    for (int nt = 0; nt < 4; ++nt) {
      const unsigned short* vb = Vt + (nt * 16 + ln) * 64;
      const bf16x8 vb0 = *(const bf16x8*)(vb + sw * 8);
      const bf16x8 vb1 = *(const bf16x8*)(vb + sw1 * 8);
      O[nt] = __builtin_amdgcn_mfma_f32_16x16x32_bf16(pa0, vb0, O[nt], 0, 0, 0);
      O[nt] = __builtin_amdgcn_mfma_f32_16x16x32_bf16(pa1, vb1, O[nt], 0, 0, 0);
    }
    __syncthreads();
  }

  // ---- stage partial O (fp32, aliases K/V) and L (aliases Ps) ----
  float* Ost = (float*)(smem + half * 16384);
  float* Lst = (float*)(smem + 32768 + half * 9216);
#pragma unroll
  for (int nt = 0; nt < 4; ++nt)
#pragma unroll
    for (int r = 0; r < 4; ++r)
      Ost[(wl * 16 + quad * 4 + r) * 64 + nt * 16 + ln] = O[nt][r];
  if (ln == 0) {
#pragma unroll
    for (int r = 0; r < 4; ++r) Lst[wl * 16 + quad * 4 + r] = Lacc[r];
  }
  __syncthreads();

  // ---- combine halves, normalize, write bf16 swizzled [B,N,DIM] ----
  const float* O0 = (const float*)smem;
  const float* O1 = (const float*)(smem + 16384);
  const float* L0 = (const float*)(smem + 32768);
  const float* L1 = (const float*)(smem + 32768 + 9216);
  const int q = t >> 3, c8 = (t & 7) * 8;
  const float inv = 1.0f / (L0[q] + L1[q]);
  const int base = q * 64 + c8;
  float4 a0 = *(const float4*)&O0[base];
  float4 a1 = *(const float4*)&O0[base + 4];
  const float4 b0 = *(const float4*)&O1[base];
  const float4 b1 = *(const float4*)&O1[base + 4];
  union { unsigned short us[8]; uint4 v; } ov;
  ov.us[0] = f2bf((a0.x + b0.x) * inv);
  ov.us[1] = f2bf((a0.y + b0.y) * inv);
  ov.us[2] = f2bf((a0.z + b0.z) * inv);
  ov.us[3] = f2bf((a0.w + b0.w) * inv);
  ov.us[4] = f2bf((a1.x + b1.x) * inv);
  ov.us[5] = f2bf((a1.y + b1.y) * inv);
  ov.us[6] = f2bf((a1.z + b1.z) * inv);
  ov.us[7] = f2bf((a1.w + b1.w) * inv);
  const int nrow = q0 + q;
  *(uint4*)&attnb[((size_t)(b * NNq + nrow)) * 512 + swzk(nrow, h * 64 + c8)] = ov.v;
}

// ---------------------------------------------------------------------------
// Staged out projection: out fp32 = attnb bf16 [4096,512] @ WoT + bo.
// 64x32 tiles, grid (64,16) = 1024 blocks; LDS 24KB -> 4 blocks/CU.
// ---------------------------------------------------------------------------
__global__ __launch_bounds__(256) void gemm_out(
    const unsigned short* __restrict__ A, const unsigned short* __restrict__ Wt,
    const float* __restrict__ bias, float* __restrict__ of) {
  __shared__ __align__(16) char sbuf[24576];  // As[64][128] | Bs[32][128]
  unsigned short* S = (unsigned short*)sbuf;
  float (*Tl)[36] = (float(*)[36])sbuf;  // aliased epilogue staging [64][36]

  const int t = threadIdx.x;
  const int w = t >> 6, lane = t & 63, ln = lane & 15, quad = lane >> 4;
  const int r0 = blockIdx.x * 64, c0 = blockIdx.y * 32;
  const int lr = lane >> 4, lc = (lane & 15) * 8;

  f32x4 acc[2];
#pragma unroll
  for (int nt = 0; nt < 2; ++nt) acc[nt] = (f32x4)(0.0f);

  for (int k0 = 0; k0 < 512; k0 += 128) {
#pragma unroll
    for (int i = 0; i < 4; ++i)
      async16(A + (size_t)(r0 + w * 16 + i * 4 + lr) * 512 + k0 + lc,
              S + (w * 16 + i * 4) * 128);
#pragma unroll
    for (int i = 0; i < 2; ++i)
      async16(Wt + (size_t)(c0 + w * 8 + i * 4 + lr) * 512 + k0 + lc,
              S + 8192 + (w * 8 + i * 4) * 128);
    __syncthreads();
#pragma unroll
    for (int kk = 0; kk < 128; kk += 32) {
      const int cp = (kk >> 3) + quad;
      const int cs = ((cp & 8) | ((cp ^ (ln & 7)) & 7)) * 8;
      const bf16x8 af = *(const bf16x8*)&S[(w * 16 + ln) * 128 + cs];
#pragma unroll
      for (int nt = 0; nt < 2; ++nt) {
        const bf16x8 bf = *(const bf16x8*)&S[8192 + (nt * 16 + ln) * 128 + cs];
        acc[nt] = __builtin_amdgcn_mfma_f32_16x16x32_bf16(af, bf, acc[nt], 0, 0, 0);
      }
    }
    __syncthreads();
  }
#pragma unroll
  for (int nt = 0; nt < 2; ++nt) {
    const float bv = bias[c0 + nt * 16 + ln];
#pragma unroll
    for (int r = 0; r < 4; ++r)
      Tl[w * 16 + quad * 4 + r][nt * 16 + ln] = acc[nt][r] + bv;
  }
  __syncthreads();
#pragma unroll
  for (int i = 0; i < 2; ++i) {
    const int idx = t + 256 * i;
    const int row = idx >> 3, c4 = (idx & 7) * 4;
    *(float4*)&of[(size_t)(r0 + row) * 512 + c0 + c4] = *(const float4*)&Tl[row][c4];
  }
}

// ---------------------------------------------------------------------------
extern "C" void kernel_launch(void* const* d_in, const int* in_sizes, int n_in,
                              void* d_out, int out_size, void* d_ws,
                              size_t ws_size, hipStream_t stream) {
  const float* z = (const float*)d_in[0];
  const float* Wq = (const float*)d_in[1];
  const float* bq = (const float*)d_in[2];
  const float* Wk = (const float*)d_in[3];
  const float* bk = (const float*)d_in[4];
  const float* Wv = (const float*)d_in[5];
  const float* bv = (const float*)d_in[6];
  const float* Wo = (const float*)d_in[7];
  const float* bo = (const float*)d_in[8];
  float* out = (float*)d_out;

  char* ws = (char*)d_ws;
  unsigned short* zb = (unsigned short*)(ws);                // 4 MiB
  unsigned short* Wt = (unsigned short*)(ws + 4194304);      // 2 MiB
  unsigned short* Qb = (unsigned short*)(ws + 6291456);      // 4 MiB
  unsigned short* Ksw = (unsigned short*)(ws + 10485760);    // 4 MiB
  unsigned short* Vsw = (unsigned short*)(ws + 14680064);    // 4 MiB
  float* c1 = (float*)(ws + 18874368);                       // 128 KiB each
  float* dv = (float*)(ws + 19005440);
  float* k2 = (float*)(ws + 19136512);
  float* q2 = (float*)(ws + 19267584);
  unsigned short* attnb = (unsigned short*)(ws + 19398656);  // 4 MiB
  unsigned int* k2max = (unsigned int*)(ws + 23592960);      // 1 KiB

  hipLaunchKernelGGL(prep_kernel, dim3(1281), dim3(256), 0, stream, z, Wq, Wk,
                     Wv, Wo, zb, Wt, k2max);
  hipLaunchKernelGGL(gemm_qkv, dim3(64, 8, 3), dim3(256), 0, stream, zb, Wt,
                     bq, bk, bv, Qb, Ksw, Vsw, c1, dv, k2, q2, k2max);
  hipLaunchKernelGGL(attn_kernel, dim3(32, 16), dim3(512), 0, stream, Qb, Ksw,
                     Vsw, c1, dv, k2, q2, k2max, attnb);
  hipLaunchKernelGGL(gemm_out, dim3(64, 16), dim3(256), 0, stream, attnb,
                     Wt + 786432, bo, out);
}